// Round 10
// baseline (4913.409 us; speedup 1.0000x reference)
//
#include <hip/hip_runtime.h>

#define B 64
#define TS 31          // T-1 steps
#define E 100
#define DY 200
#define DZ 500
#define V 32000
#define H 700
#define HP 704         // padded H (mult of 32) for MFMA K
#define H3 2100
#define XH 800         // xh row: x (cols 0..99) then h (cols 100..799)
#define SOS 2
#define OUT_PRED_OFF (33*B*H)   // outputs [33,64,700] then predictions [32,64,32000]
#define VCH 125        // v's per k3 chunk
#define NVCH 256       // 256*125 = 32000
#define NT1 33         // 64-wide n-tiles over 2100
#define NPB 500        // k2_pred blocks (V/64) -> softmax partials per row
#define NPBP 512       // padded stride

typedef unsigned short u16;
typedef __attribute__((ext_vector_type(8))) short short8;
typedef __attribute__((ext_vector_type(4))) float f32x4;

__device__ __forceinline__ float sigm(float x) { return 1.f / (1.f + __expf(-x)); }
__device__ __forceinline__ u16 f2b(float f) {
  union { float f; unsigned int u; } c; c.f = f;
  unsigned int u = c.u;
  u16 h = (u16)(u >> 16);
  unsigned int rem = u & 0xFFFFu;
  h += (u16)((rem > 0x8000u) || (rem == 0x8000u && (h & 1)));
  return h;
}

// ---------------- fallback: zero entire out (signature 0.4121094) ----------------
__global__ __launch_bounds__(256) void k_zero(float* __restrict__ out, long n) {
  long i0 = (long)blockIdx.x * 256 + threadIdx.x;
  long st = (long)gridDim.x * 256;
  for (long i = i0; i < n; i += st) out[i] = 0.f;
}

// ---------------- init: zeros, h0, x0, WT(f32), W_bf(bf16), h_bf pad ----------------
__global__ __launch_bounds__(256) void k0_init(
    const float* __restrict__ z, const float* __restrict__ labels,
    const float* __restrict__ W_fc, const float* __restrict__ b_fc,
    const float* __restrict__ embed, const float* __restrict__ W_ih,
    const float* __restrict__ W_hh, const float* __restrict__ W_out,
    float* __restrict__ out, float* __restrict__ xhA, float* __restrict__ WT,
    u16* __restrict__ W_bf, u16* __restrict__ h_bf)
{
  long i0 = (long)blockIdx.x * 256 + threadIdx.x;
  long st = (long)gridDim.x * 256;
  for (long i = i0; i < (long)B * V; i += st) out[OUT_PRED_OFF + i] = 0.f;
  for (long i = i0; i < (long)B * H; i += st) out[B * H + i] = 0.f;
  for (long i = i0; i < (long)B * H; i += st) {
    int b = (int)(i / H), j = (int)(i % H);
    float v = (j < DY) ? (1.f - labels[b]) * W_fc[j] + b_fc[j]
                       : z[b * DZ + (j - DY)];
    xhA[b * XH + 100 + j] = v;
    out[i] = v;
  }
  for (long i = i0; i < (long)B * E; i += st) {
    int b = (int)(i / E), e = (int)(i % E);
    xhA[b * XH + e] = embed[SOS * E + e];
  }
  for (long i = i0; i < (long)B * HP; i += st) h_bf[i] = 0;
  for (long i = i0; i < (long)XH * H3; i += st) {
    int k = (int)(i / H3), g = (int)(i % H3);
    WT[i] = (k < E) ? W_ih[(long)g * E + k] : W_hh[(long)g * H + (k - E)];
  }
  for (long i = i0; i < (long)V * HP; i += st) {
    int v = (int)(i / HP), j = (int)(i % HP);
    W_bf[i] = (j < H) ? f2b(W_out[(long)v * H + j]) : (u16)0;
  }
}

// ---------------- per-step: gates GEMM, K-split (c: 0=x-part, 1..7=h-part) ----------------
__global__ __launch_bounds__(256) void k1a(
    const float* __restrict__ xh, const float* __restrict__ WT,
    const float* __restrict__ b_ih,
    float* __restrict__ gig, float* __restrict__ ghg_p)
{
  int nt = blockIdx.x, c = blockIdx.y;
  int n = nt * 64 + (threadIdx.x & 63);
  int bq = threadIdx.x >> 6;                 // 4 groups of 16 b
  __shared__ float xs[64][100];
  for (int i = threadIdx.x; i < 6400; i += 256) {
    int b = i / 100, kk = i % 100;
    xs[b][kk] = xh[b * XH + c * 100 + kk];
  }
  __syncthreads();
  if (n >= H3) return;
  float acc[16];
  #pragma unroll
  for (int bb = 0; bb < 16; ++bb) acc[bb] = 0.f;
  for (int kk = 0; kk < 100; ++kk) {
    float w = WT[(size_t)(c * 100 + kk) * H3 + n];
    #pragma unroll
    for (int bb = 0; bb < 16; ++bb) acc[bb] += xs[bq * 16 + bb][kk] * w;
  }
  if (c == 0) {
    float bi = b_ih[n];
    #pragma unroll
    for (int bb = 0; bb < 16; ++bb) gig[(size_t)(bq * 16 + bb) * H3 + n] = acc[bb] + bi;
  } else {
    float* p = ghg_p + (size_t)(c - 1) * B * H3;
    #pragma unroll
    for (int bb = 0; bb < 16; ++bb) p[(size_t)(bq * 16 + bb) * H3 + n] = acc[bb];
  }
}

// ---------------- per-step: reduce gh partials + gates + h update (+zero x-part) ----------------
__global__ __launch_bounds__(256) void k1br(
    const float* __restrict__ gig, const float* __restrict__ ghg_p,
    const float* __restrict__ b_hh, const float* __restrict__ xh_in,
    float* __restrict__ xh_out, float* __restrict__ out_h, u16* __restrict__ h_bf)
{
  int i = blockIdx.x * 256 + threadIdx.x;    // B*H = 44800
  if (i >= B * H) return;
  int b = i / H, j = i % H;
  float ir = gig[(size_t)b * H3 + j];
  float iz = gig[(size_t)b * H3 + H + j];
  float in_ = gig[(size_t)b * H3 + 2 * H + j];
  float hr = b_hh[j], hz = b_hh[H + j], hn = b_hh[2 * H + j];
  for (int c = 0; c < 7; ++c) {
    const float* p = ghg_p + (size_t)c * B * H3 + (size_t)b * H3;
    hr += p[j]; hz += p[H + j]; hn += p[2 * H + j];
  }
  float hprev = xh_in[b * XH + 100 + j];
  float r  = sigm(ir + hr);
  float zt = sigm(iz + hz);
  float nn = tanhf(in_ + r * hn);
  float hv = (1.f - zt) * nn + zt * hprev;
  xh_out[b * XH + 100 + j] = hv;
  out_h[i] = hv;
  h_bf[b * HP + j] = f2b(hv);
  if (j < 100) xh_out[b * XH + j] = 0.f;   // x-part accumulated by k3_embed atomics
}

// ---------------- per-step: pred GEMM + gumbel + per-block softmax partials ----------------
__global__ __launch_bounds__(256) void k2_pred(
    const u16* __restrict__ h_bf,   // [B][HP], pad cols 0
    const u16* __restrict__ W_bf,   // [V][HP], pad cols 0
    const float* __restrict__ b_out,
    const float* __restrict__ gu,   // + t*B*V
    float* __restrict__ out_pred,   // f32, predictions slice of d_out
    float* __restrict__ S,          // [B][V] s = pred+g
    float* __restrict__ part_m,     // [B][NPBP]
    float* __restrict__ part_z)     // [B][NPBP]
{
  int wave = threadIdx.x >> 6, lane = threadIdx.x & 63;
  int n0 = blockIdx.x * 64;
  int rowa = (wave << 4) + (lane & 15);
  int kq = (lane >> 4) << 3;
  f32x4 acc[4];
  #pragma unroll
  for (int t = 0; t < 4; ++t) acc[t] = f32x4{0.f, 0.f, 0.f, 0.f};
  for (int k = 0; k < HP; k += 32) {
    short8 a = *reinterpret_cast<const short8*>(h_bf + (size_t)rowa * HP + k + kq);
    #pragma unroll
    for (int t = 0; t < 4; ++t) {
      int col = n0 + (t << 4) + (lane & 15);
      short8 bv = *reinterpret_cast<const short8*>(W_bf + (size_t)col * HP + k + kq);
      acc[t] = __builtin_amdgcn_mfma_f32_16x16x32_bf16(a, bv, acc[t], 0, 0, 0);
    }
  }
  int colbase = n0 + (lane & 15);
  #pragma unroll
  for (int r = 0; r < 4; ++r) {
    int brow = (wave << 4) + ((lane >> 4) << 2) + r;  // C/D: col=lane&15, row=(lane>>4)*4+r
    float vm = -1e30f, vz = 0.f;
    #pragma unroll
    for (int t = 0; t < 4; ++t) {
      int col = colbase + (t << 4);
      float pred = acc[t][r] + b_out[col];
      size_t off = (size_t)brow * V + col;
      out_pred[off] = pred;
      float u = gu[off];
      float g = -logf(-logf(u + 1e-10f) + 1e-10f);   // libm for near-1 accuracy
      float s = pred + g;
      S[off] = s;
      if (s > vm) { vz = vz * __expf(vm - s) + 1.f; vm = s; }
      else vz += __expf(s - vm);
    }
    // butterfly across the 16 lanes sharing this row (lane&15 varies)
    #pragma unroll
    for (int msk = 1; msk < 16; msk <<= 1) {
      float om = __shfl_xor(vm, msk);
      float oz = __shfl_xor(vz, msk);
      float nm = fmaxf(vm, om);
      vz = vz * __expf(vm - nm) + oz * __expf(om - nm);
      vm = nm;
    }
    if ((lane & 15) == 0) {
      part_m[(size_t)brow * NPBP + blockIdx.x] = vm;
      part_z[(size_t)brow * NPBP + blockIdx.x] = vz;
    }
  }
}

// ---------------- per-step: combine partials, y inline, embed GEMM, atomic x ----------------
__global__ __launch_bounds__(256) void k3_embed(
    const float* __restrict__ S, const float* __restrict__ part_m,
    const float* __restrict__ part_z, const float* __restrict__ embed,
    float* __restrict__ xh_out)
{
  __shared__ float Ms[64], Is[64];
  __shared__ float ys[64][VCH];
  int tid = threadIdx.x;
  int v0 = blockIdx.x * VCH;
  {
    int b = tid >> 2, q = tid & 3;
    const float* pm = part_m + (size_t)b * NPBP;
    const float* pz = part_z + (size_t)b * NPBP;
    float m = -1e30f;
    for (int i = q; i < NPB; i += 4) m = fmaxf(m, pm[i]);
    m = fmaxf(m, __shfl_xor(m, 1));
    m = fmaxf(m, __shfl_xor(m, 2));
    float zz = 0.f;
    for (int i = q; i < NPB; i += 4) zz += pz[i] * __expf(pm[i] - m);
    zz += __shfl_xor(zz, 1);
    zz += __shfl_xor(zz, 2);
    if (q == 0) { Ms[b] = m; Is[b] = 2.f / zz; }   // y/GAMMA = 2*softmax
  }
  __syncthreads();
  for (int i = tid; i < 64 * VCH; i += 256) {
    int b = i / VCH, vv = i % VCH;
    ys[b][vv] = __expf(S[(size_t)b * V + v0 + vv] - Ms[b]) * Is[b];
  }
  __syncthreads();
  int e = tid & 127, bh = tid >> 7;   // bh: 2 groups of 32 b
  if (e >= E) return;
  float acc[32];
  #pragma unroll
  for (int bb = 0; bb < 32; ++bb) acc[bb] = 0.f;
  for (int vv = 0; vv < VCH; ++vv) {
    float w = embed[(size_t)(v0 + vv) * E + e];
    #pragma unroll
    for (int bb = 0; bb < 32; ++bb) acc[bb] += ys[bh * 32 + bb][vv] * w;
  }
  #pragma unroll
  for (int bb = 0; bb < 32; ++bb)
    atomicAdd(&xh_out[(size_t)(bh * 32 + bb) * XH + e], acc[bb]);
}

extern "C" void kernel_launch(void* const* d_in, const int* in_sizes, int n_in,
                              void* d_out, int out_size, void* d_ws, size_t ws_size,
                              hipStream_t stream) {
  (void)ws_size;
  float* out = (float*)d_out;

  // ---- resolve input permutation from in_sizes (host-side, deterministic) ----
  static const long lsz[12] = {32000, 64, 200, 200, 3200000, 210000, 1470000,
                               2100, 2100, 22400000, 32000, 63488000};
  static const int dictP[12]    = {0, 1, 2, 3, 4, 5, 6, 7, 8, 9, 10, 11};
  static const int alpha14P[12] = {13, 10, 0, 4, 8, 2, 1, 6, 5, 3, 7, 9};
  static const int alpha12P[12] = {11, 10, 0, 4, 8, 2, 1, 6, 5, 3, 7, 9};
  auto okperm = [&](const int* p) -> bool {
    for (int i = 0; i < 12; ++i) {
      if (p[i] >= n_in) return false;
      if ((long)in_sizes[p[i]] != lsz[i]) return false;
    }
    return true;
  };
  const int* P = nullptr;
  if (okperm(dictP)) P = dictP;
  else if (okperm(alpha14P)) P = alpha14P;
  else if (okperm(alpha12P)) P = alpha12P;
  if (!P) { k_zero<<<2048, 256, 0, stream>>>(out, (long)out_size); return; }

  const float* z      = (const float*)d_in[P[0]];
  const float* labels = (const float*)d_in[P[1]];
  const float* W_fc   = (const float*)d_in[P[2]];
  const float* b_fc   = (const float*)d_in[P[3]];
  const float* embed  = (const float*)d_in[P[4]];
  const float* W_ih   = (const float*)d_in[P[5]];
  const float* W_hh   = (const float*)d_in[P[6]];
  const float* b_ih   = (const float*)d_in[P[7]];
  const float* b_hh   = (const float*)d_in[P[8]];
  const float* W_out  = (const float*)d_in[P[9]];
  const float* b_out  = (const float*)d_in[P[10]];
  const float* gu     = (const float*)d_in[P[11]];

  char* w = (char*)d_ws;
  auto alloc = [&](size_t bytes) { char* p = w; w += (bytes + 255) & ~(size_t)255; return p; };
  float* xhA    = (float*)alloc((size_t)B * XH * 4);
  float* xhB    = (float*)alloc((size_t)B * XH * 4);
  float* WT     = (float*)alloc((size_t)XH * H3 * 4);
  float* gig    = (float*)alloc((size_t)B * H3 * 4);
  float* ghg_p  = (float*)alloc((size_t)7 * B * H3 * 4);
  float* S      = (float*)alloc((size_t)B * V * 4);
  float* part_m = (float*)alloc((size_t)B * NPBP * 4);
  float* part_z = (float*)alloc((size_t)B * NPBP * 4);
  u16*  W_bf    = (u16*)alloc((size_t)V * HP * 2);
  u16*  h_bf    = (u16*)alloc((size_t)B * HP * 2);

  k0_init<<<2048, 256, 0, stream>>>(z, labels, W_fc, b_fc, embed, W_ih, W_hh, W_out,
                                    out, xhA, WT, W_bf, h_bf);

  for (int t = 0; t < TS; ++t) {
    float* xin  = (t & 1) ? xhB : xhA;
    float* xout = (t & 1) ? xhA : xhB;
    float* pred = out + OUT_PRED_OFF + (size_t)(1 + t) * B * V;
    k1a<<<dim3(NT1, 8), 256, 0, stream>>>(xin, WT, b_ih, gig, ghg_p);
    k1br<<<(B * H + 255) / 256, 256, 0, stream>>>(gig, ghg_p, b_hh, xin, xout,
                                                  out + (size_t)(2 + t) * B * H, h_bf);
    k2_pred<<<NPB, 256, 0, stream>>>(h_bf, W_bf, b_out, gu + (size_t)t * B * V,
                                     pred, S, part_m, part_z);
    k3_embed<<<NVCH, 256, 0, stream>>>(S, part_m, part_z, embed, xout);
  }
}

// Round 11
// 4738.927 us; speedup vs baseline: 1.0368x; 1.0368x over previous
//
#include <hip/hip_runtime.h>

#define B 64
#define TS 31          // T-1 steps
#define E 100
#define DY 200
#define DZ 500
#define V 32000
#define H 700
#define HP 704         // padded H (mult of 32) for MFMA K
#define H3 2100
#define XH 800         // xh row: x (cols 0..99) then h (cols 100..799)
#define SOS 2
#define OUT_PRED_OFF (33*B*H)   // outputs [33,64,700] then predictions [32,64,32000]
#define VCH 125        // v's per k3 chunk
#define NVCH 256       // 256*125 = 32000
#define NT1 33         // 64-wide n-tiles over 2100
#define NPB 500        // k2_pred blocks (V/64) -> softmax partials per row
#define NPBP 512       // padded stride

typedef unsigned short u16;
typedef __attribute__((ext_vector_type(8))) short short8;
typedef __attribute__((ext_vector_type(4))) float f32x4;

__device__ __forceinline__ float sigm(float x) { return 1.f / (1.f + __expf(-x)); }
__device__ __forceinline__ u16 f2b(float f) {
  union { float f; unsigned int u; } c; c.f = f;
  unsigned int u = c.u;
  u16 h = (u16)(u >> 16);
  unsigned int rem = u & 0xFFFFu;
  h += (u16)((rem > 0x8000u) || (rem == 0x8000u && (h & 1)));
  return h;
}

// ---------------- fallback: zero entire out (signature 0.4121094) ----------------
__global__ __launch_bounds__(256) void k_zero(float* __restrict__ out, long n) {
  long i0 = (long)blockIdx.x * 256 + threadIdx.x;
  long st = (long)gridDim.x * 256;
  for (long i = i0; i < n; i += st) out[i] = 0.f;
}

// ---------------- init: zeros, h0, x0, WT(f32), W_bf(bf16), h_bf, gh ----------------
__global__ __launch_bounds__(256) void k0_init(
    const float* __restrict__ z, const float* __restrict__ labels,
    const float* __restrict__ W_fc, const float* __restrict__ b_fc,
    const float* __restrict__ embed, const float* __restrict__ W_ih,
    const float* __restrict__ W_hh, const float* __restrict__ W_out,
    float* __restrict__ out, float* __restrict__ xhA, float* __restrict__ WT,
    u16* __restrict__ W_bf, u16* __restrict__ h_bf, float* __restrict__ gh)
{
  long i0 = (long)blockIdx.x * 256 + threadIdx.x;
  long st = (long)gridDim.x * 256;
  for (long i = i0; i < (long)B * V; i += st) out[OUT_PRED_OFF + i] = 0.f;
  for (long i = i0; i < (long)B * H; i += st) out[B * H + i] = 0.f;
  for (long i = i0; i < (long)B * H; i += st) {
    int b = (int)(i / H), j = (int)(i % H);
    float v = (j < DY) ? (1.f - labels[b]) * W_fc[j] + b_fc[j]
                       : z[b * DZ + (j - DY)];
    xhA[b * XH + 100 + j] = v;
    out[i] = v;
  }
  for (long i = i0; i < (long)B * E; i += st) {
    int b = (int)(i / E), e = (int)(i % E);
    xhA[b * XH + e] = embed[SOS * E + e];
  }
  for (long i = i0; i < (long)B * HP; i += st) h_bf[i] = 0;
  for (long i = i0; i < (long)B * H3; i += st) gh[i] = 0.f;
  for (long i = i0; i < (long)XH * H3; i += st) {
    int k = (int)(i / H3), g = (int)(i % H3);
    WT[i] = (k < E) ? W_ih[(long)g * E + k] : W_hh[(long)g * H + (k - E)];
  }
  for (long i = i0; i < (long)V * HP; i += st) {
    int v = (int)(i / HP), j = (int)(i % HP);
    W_bf[i] = (j < H) ? f2b(W_out[(long)v * H + j]) : (u16)0;
  }
}

// ---------------- per-step: gates GEMM, K-split; c==0 -> gi store, c>0 -> gh atomic ----------------
__global__ __launch_bounds__(256) void k1a(
    const float* __restrict__ xh, const float* __restrict__ WT,
    const float* __restrict__ b_ih,
    float* __restrict__ gi, float* __restrict__ gh)
{
  int nt = blockIdx.x, c = blockIdx.y;
  int n = nt * 64 + (threadIdx.x & 63);
  int bq = threadIdx.x >> 6;                 // 4 groups of 16 b
  __shared__ float xs[64][100];
  for (int i = threadIdx.x; i < 6400; i += 256) {
    int b = i / 100, kk = i % 100;
    xs[b][kk] = xh[b * XH + c * 100 + kk];
  }
  __syncthreads();
  if (n >= H3) return;
  float acc[16];
  #pragma unroll
  for (int bb = 0; bb < 16; ++bb) acc[bb] = 0.f;
  for (int kk = 0; kk < 100; kk += 4) {
    const float* wr = &WT[(size_t)(c * 100 + kk) * H3 + n];
    float w0 = wr[0], w1 = wr[H3], w2 = wr[2 * H3], w3 = wr[3 * H3];
    #pragma unroll
    for (int bb = 0; bb < 16; ++bb) {
      float4 x = *reinterpret_cast<const float4*>(&xs[bq * 16 + bb][kk]);
      acc[bb] += x.x * w0 + x.y * w1 + x.z * w2 + x.w * w3;
    }
  }
  if (c == 0) {
    float bi = b_ih[n];
    #pragma unroll
    for (int bb = 0; bb < 16; ++bb) gi[(size_t)(bq * 16 + bb) * H3 + n] = acc[bb] + bi;
  } else {
    #pragma unroll
    for (int bb = 0; bb < 16; ++bb)
      atomicAdd(&gh[(size_t)(bq * 16 + bb) * H3 + n], acc[bb]);
  }
}

// ---------------- per-step: gates + h update (+zero x-part of xh_out) ----------------
__global__ __launch_bounds__(256) void k1br(
    const float* __restrict__ gi, const float* __restrict__ gh,
    const float* __restrict__ b_hh, const float* __restrict__ xh_in,
    float* __restrict__ xh_out, float* __restrict__ out_h, u16* __restrict__ h_bf)
{
  int i = blockIdx.x * 256 + threadIdx.x;    // B*H = 44800
  if (i >= B * H) return;
  int b = i / H, j = i % H;
  float ir = gi[(size_t)b * H3 + j];
  float iz = gi[(size_t)b * H3 + H + j];
  float in_ = gi[(size_t)b * H3 + 2 * H + j];
  float hr = gh[(size_t)b * H3 + j] + b_hh[j];
  float hz = gh[(size_t)b * H3 + H + j] + b_hh[H + j];
  float hn = gh[(size_t)b * H3 + 2 * H + j] + b_hh[2 * H + j];
  float hprev = xh_in[b * XH + 100 + j];
  float r  = sigm(ir + hr);
  float zt = sigm(iz + hz);
  float nn = tanhf(in_ + r * hn);
  float hv = (1.f - zt) * nn + zt * hprev;
  xh_out[b * XH + 100 + j] = hv;
  out_h[i] = hv;
  h_bf[b * HP + j] = f2b(hv);
  if (j < 100) xh_out[b * XH + j] = 0.f;   // x-part accumulated by k3_embed atomics
}

// ---------------- per-step: pred GEMM (col-per-wave) + gumbel + block partials ----------------
__global__ __launch_bounds__(256) void k2_pred(
    const u16* __restrict__ h_bf,   // [B][HP], pad cols 0
    const u16* __restrict__ W_bf,   // [V][HP], pad cols 0
    const float* __restrict__ b_out,
    const float* __restrict__ gu,   // + t*B*V
    float* __restrict__ out_pred,   // f32, predictions slice of d_out
    float* __restrict__ S,          // [B][V] s = pred+g
    float* __restrict__ part_m,     // [B][NPBP]
    float* __restrict__ part_z,     // [B][NPBP]
    float* __restrict__ gh)         // zeroed here for next step's k1a
{
  int wave = threadIdx.x >> 6, lane = threadIdx.x & 63;
  int l15 = lane & 15;
  int col = blockIdx.x * 64 + wave * 16 + l15;   // wave owns 16 cols -> W read once/block
  int kq = (lane >> 4) << 3;
  f32x4 acc[4];
  #pragma unroll
  for (int t = 0; t < 4; ++t) acc[t] = f32x4{0.f, 0.f, 0.f, 0.f};
  const u16* wp = W_bf + (size_t)col * HP + kq;
  const u16* hp = h_bf + kq;
  for (int k = 0; k < HP; k += 32) {
    short8 bv = *reinterpret_cast<const short8*>(wp + k);
    #pragma unroll
    for (int rt = 0; rt < 4; ++rt) {
      short8 a = *reinterpret_cast<const short8*>(hp + (size_t)(rt * 16 + l15) * HP + k);
      acc[rt] = __builtin_amdgcn_mfma_f32_16x16x32_bf16(a, bv, acc[rt], 0, 0, 0);
    }
  }
  __shared__ float lm[64][4], lz[64][4];
  float bo = b_out[col];
  #pragma unroll
  for (int rt = 0; rt < 4; ++rt) {
    #pragma unroll
    for (int r = 0; r < 4; ++r) {
      int brow = rt * 16 + ((lane >> 4) << 2) + r;  // C/D: col=lane&15, row=(lane>>4)*4+r
      float pred = acc[rt][r] + bo;
      size_t off = (size_t)brow * V + col;
      out_pred[off] = pred;
      float u = gu[off];
      float g = -logf(-logf(u + 1e-10f) + 1e-10f);   // libm for accuracy
      float s = pred + g;
      S[off] = s;
      float vm = s, vz = 1.f;
      #pragma unroll
      for (int msk = 1; msk < 16; msk <<= 1) {
        float om = __shfl_xor(vm, msk);
        float oz = __shfl_xor(vz, msk);
        float nm = fmaxf(vm, om);
        vz = vz * __expf(vm - nm) + oz * __expf(om - nm);
        vm = nm;
      }
      if (l15 == 0) { lm[brow][wave] = vm; lz[brow][wave] = vz; }
    }
  }
  __syncthreads();
  if (threadIdx.x < 64) {
    int b = threadIdx.x;
    float m0 = fmaxf(fmaxf(lm[b][0], lm[b][1]), fmaxf(lm[b][2], lm[b][3]));
    float zz = lz[b][0] * __expf(lm[b][0] - m0) + lz[b][1] * __expf(lm[b][1] - m0)
             + lz[b][2] * __expf(lm[b][2] - m0) + lz[b][3] * __expf(lm[b][3] - m0);
    part_m[(size_t)b * NPBP + blockIdx.x] = m0;
    part_z[(size_t)b * NPBP + blockIdx.x] = zz;
  }
  for (int i = blockIdx.x * 256 + threadIdx.x; i < B * H3; i += NPB * 256) gh[i] = 0.f;
}

// ---------------- per-step: combine partials, y inline, embed GEMM, atomic x ----------------
__global__ __launch_bounds__(256) void k3_embed(
    const float* __restrict__ S, const float* __restrict__ part_m,
    const float* __restrict__ part_z, const float* __restrict__ embed,
    float* __restrict__ xh_out)
{
  __shared__ float Ms[64], Is[64];
  __shared__ float ys[64][VCH];
  int tid = threadIdx.x;
  int v0 = blockIdx.x * VCH;
  {
    int b = tid >> 2, q = tid & 3;
    const float* pm = part_m + (size_t)b * NPBP;
    const float* pz = part_z + (size_t)b * NPBP;
    float m = -1e30f;
    for (int i = q; i < NPB; i += 4) m = fmaxf(m, pm[i]);
    m = fmaxf(m, __shfl_xor(m, 1));
    m = fmaxf(m, __shfl_xor(m, 2));
    float zz = 0.f;
    for (int i = q; i < NPB; i += 4) zz += pz[i] * __expf(pm[i] - m);
    zz += __shfl_xor(zz, 1);
    zz += __shfl_xor(zz, 2);
    if (q == 0) { Ms[b] = m; Is[b] = 2.f / zz; }   // y/GAMMA = 2*softmax
  }
  __syncthreads();
  for (int i = tid; i < 64 * VCH; i += 256) {
    int b = i / VCH, vv = i % VCH;
    ys[b][vv] = __expf(S[(size_t)b * V + v0 + vv] - Ms[b]) * Is[b];
  }
  __syncthreads();
  int e = tid & 127, bh = tid >> 7;   // bh: 2 groups of 32 b
  if (e >= E) return;
  float acc[32];
  #pragma unroll
  for (int bb = 0; bb < 32; ++bb) acc[bb] = 0.f;
  for (int vv = 0; vv < VCH; ++vv) {
    float w = embed[(size_t)(v0 + vv) * E + e];
    #pragma unroll
    for (int bb = 0; bb < 32; ++bb) acc[bb] += ys[bh * 32 + bb][vv] * w;
  }
  #pragma unroll
  for (int bb = 0; bb < 32; ++bb)
    atomicAdd(&xh_out[(size_t)(bh * 32 + bb) * XH + e], acc[bb]);
}

extern "C" void kernel_launch(void* const* d_in, const int* in_sizes, int n_in,
                              void* d_out, int out_size, void* d_ws, size_t ws_size,
                              hipStream_t stream) {
  (void)ws_size;
  float* out = (float*)d_out;

  // ---- resolve input permutation from in_sizes (host-side, deterministic) ----
  static const long lsz[12] = {32000, 64, 200, 200, 3200000, 210000, 1470000,
                               2100, 2100, 22400000, 32000, 63488000};
  static const int dictP[12]    = {0, 1, 2, 3, 4, 5, 6, 7, 8, 9, 10, 11};
  static const int alpha14P[12] = {13, 10, 0, 4, 8, 2, 1, 6, 5, 3, 7, 9};
  static const int alpha12P[12] = {11, 10, 0, 4, 8, 2, 1, 6, 5, 3, 7, 9};
  auto okperm = [&](const int* p) -> bool {
    for (int i = 0; i < 12; ++i) {
      if (p[i] >= n_in) return false;
      if ((long)in_sizes[p[i]] != lsz[i]) return false;
    }
    return true;
  };
  const int* P = nullptr;
  if (okperm(dictP)) P = dictP;
  else if (okperm(alpha14P)) P = alpha14P;
  else if (okperm(alpha12P)) P = alpha12P;
  if (!P) { k_zero<<<2048, 256, 0, stream>>>(out, (long)out_size); return; }

  const float* z      = (const float*)d_in[P[0]];
  const float* labels = (const float*)d_in[P[1]];
  const float* W_fc   = (const float*)d_in[P[2]];
  const float* b_fc   = (const float*)d_in[P[3]];
  const float* embed  = (const float*)d_in[P[4]];
  const float* W_ih   = (const float*)d_in[P[5]];
  const float* W_hh   = (const float*)d_in[P[6]];
  const float* b_ih   = (const float*)d_in[P[7]];
  const float* b_hh   = (const float*)d_in[P[8]];
  const float* W_out  = (const float*)d_in[P[9]];
  const float* b_out  = (const float*)d_in[P[10]];
  const float* gu     = (const float*)d_in[P[11]];

  char* w = (char*)d_ws;
  auto alloc = [&](size_t bytes) { char* p = w; w += (bytes + 255) & ~(size_t)255; return p; };
  float* xhA    = (float*)alloc((size_t)B * XH * 4);
  float* xhB    = (float*)alloc((size_t)B * XH * 4);
  float* WT     = (float*)alloc((size_t)XH * H3 * 4);
  float* gi     = (float*)alloc((size_t)B * H3 * 4);
  float* gh     = (float*)alloc((size_t)B * H3 * 4);
  float* S      = (float*)alloc((size_t)B * V * 4);
  float* part_m = (float*)alloc((size_t)B * NPBP * 4);
  float* part_z = (float*)alloc((size_t)B * NPBP * 4);
  u16*  W_bf    = (u16*)alloc((size_t)V * HP * 2);
  u16*  h_bf    = (u16*)alloc((size_t)B * HP * 2);

  k0_init<<<2048, 256, 0, stream>>>(z, labels, W_fc, b_fc, embed, W_ih, W_hh, W_out,
                                    out, xhA, WT, W_bf, h_bf, gh);

  for (int t = 0; t < TS; ++t) {
    float* xin  = (t & 1) ? xhB : xhA;
    float* xout = (t & 1) ? xhA : xhB;
    float* pred = out + OUT_PRED_OFF + (size_t)(1 + t) * B * V;
    k1a<<<dim3(NT1, 8), 256, 0, stream>>>(xin, WT, b_ih, gi, gh);
    k1br<<<(B * H + 255) / 256, 256, 0, stream>>>(gi, gh, b_hh, xin, xout,
                                                  out + (size_t)(2 + t) * B * H, h_bf);
    k2_pred<<<NPB, 256, 0, stream>>>(h_bf, W_bf, b_out, gu + (size_t)t * B * V,
                                     pred, S, part_m, part_z, gh);
    k3_embed<<<NVCH, 256, 0, stream>>>(S, part_m, part_z, embed, xout);
  }
}